// Round 1
// baseline (67.259 us; speedup 1.0000x reference)
//
#include <hip/hip_runtime.h>
#include <math.h>

#define NB   4
#define NPTS 4096
#define BN   (NB * NPTS)

__device__ inline float wave_sum(float v) {
#pragma unroll
    for (int o = 32; o > 0; o >>= 1) v += __shfl_xor(v, o);
    return v;
}

// Block-wide (256-thread) sum; result broadcast to all threads.
__device__ inline float block_sum_256(float v, float* sbuf) {
    int lane = threadIdx.x & 63, w = threadIdx.x >> 6;
    v = wave_sum(v);
    __syncthreads();              // protect sbuf reuse
    if (lane == 0) sbuf[w] = v;
    __syncthreads();
    return sbuf[0] + sbuf[1] + sbuf[2] + sbuf[3];
}

// --- Kernel 1: per-batch variance of distances to centroid (ddof=1) ---
__global__ __launch_bounds__(256) void var_kernel(const float* __restrict__ pc,
                                                  float* __restrict__ vout) {
    __shared__ float sbuf[4];
    int b = blockIdx.x;
    const float* p = pc + (size_t)b * NPTS * 3;
    int t = threadIdx.x;

    float sx = 0.f, sy = 0.f, sz = 0.f;
    for (int i = t; i < NPTS; i += 256) {
        sx += p[3*i+0]; sy += p[3*i+1]; sz += p[3*i+2];
    }
    float cx = block_sum_256(sx, sbuf) * (1.f / NPTS);
    float cy = block_sum_256(sy, sbuf) * (1.f / NPTS);
    float cz = block_sum_256(sz, sbuf) * (1.f / NPTS);

    float s1 = 0.f, s2 = 0.f;
    for (int i = t; i < NPTS; i += 256) {
        float dx = p[3*i+0] - cx, dy = p[3*i+1] - cy, dz = p[3*i+2] - cz;
        float d2 = fmaf(dx, dx, fmaf(dy, dy, dz * dz));
        s1 += sqrtf(d2);
        s2 += d2;
    }
    float S1 = block_sum_256(s1, sbuf);
    float S2 = block_sum_256(s2, sbuf);
    if (t == 0)
        vout[b] = (S2 - S1 * S1 * (1.f / NPTS)) * (1.f / (NPTS - 1));
}

// --- Kernel 2: partial nearest-neighbor min over one j-chunk ---
// grid = 64 * NJ blocks of 256 threads. Block handles 256 query points
// (one per thread, point held in registers) vs a JC-point chunk staged in LDS.
template <int NJ>
__global__ __launch_bounds__(256) void nn_kernel(const float* __restrict__ pc,
                                                 float* __restrict__ pmin) {
    constexpr int JC = NPTS / NJ;
    __shared__ float4 lpt[JC];

    int blk = blockIdx.x;
    int jc  = blk % NJ;
    int qb  = blk / NJ;          // 0..63 global query block
    int b   = qb >> 4;           // 16 query blocks per batch
    int iq0 = (qb & 15) * 256;   // query offset within batch
    const float* p = pc + (size_t)b * NPTS * 3;
    int t = threadIdx.x;
    int jbase = jc * JC;

    for (int j = t; j < JC; j += 256) {
        int jg = jbase + j;
        lpt[j] = make_float4(p[3*jg+0], p[3*jg+1], p[3*jg+2], 0.f);
    }
    __syncthreads();

    int i = iq0 + t;
    float xi = p[3*i+0], yi = p[3*i+1], zi = p[3*i+2];
    float m = 1e30f;

    if (jc == iq0 / JC) {
        // this chunk contains the diagonal for every query in the block
        int idiag = i - jbase;
#pragma unroll 8
        for (int j = 0; j < JC; ++j) {
            float4 q = lpt[j];
            float dx = xi - q.x, dy = yi - q.y, dz = zi - q.z;
            float d2 = fmaf(dx, dx, fmaf(dy, dy, dz * dz));
            m = fminf(m, (j == idiag) ? 1e30f : d2);
        }
    } else {
#pragma unroll 8
        for (int j = 0; j < JC; ++j) {
            float4 q = lpt[j];
            float dx = xi - q.x, dy = yi - q.y, dz = zi - q.z;
            float d2 = fmaf(dx, dx, fmaf(dy, dy, dz * dz));
            m = fminf(m, d2);
        }
    }
    pmin[(size_t)jc * BN + (size_t)b * NPTS + i] = m;
}

// --- Kernel 3: combine partial mins, exp penalty, final scalar ---
template <int NJ>
__global__ __launch_bounds__(1024) void final_kernel(const float* __restrict__ pmin,
                                                     const float* __restrict__ vars,
                                                     float* __restrict__ out) {
    __shared__ float sbuf[16];
    int t = threadIdx.x;
    float s = 0.f;
    for (int g = t; g < BN; g += 1024) {
        float m = pmin[g];
#pragma unroll
        for (int jc = 1; jc < NJ; ++jc)
            m = fminf(m, pmin[(size_t)jc * BN + g]);
        s += __expf(-5.f * m);
    }
    int lane = t & 63, w = t >> 6;
    s = wave_sum(s);
    if (lane == 0) sbuf[w] = s;
    __syncthreads();
    if (t == 0) {
        float tot = 0.f;
#pragma unroll
        for (int k = 0; k < 16; ++k) tot += sbuf[k];
        float v = 0.25f * (vars[0] + vars[1] + vars[2] + vars[3]);
        out[0] = v + tot * (1.f / BN);
    }
}

extern "C" void kernel_launch(void* const* d_in, const int* in_sizes, int n_in,
                              void* d_out, int out_size, void* d_ws, size_t ws_size,
                              hipStream_t stream) {
    const float* pc = (const float*)d_in[0];
    float* out  = (float*)d_out;
    float* vars = (float*)d_ws;
    float* pmin = (float*)((char*)d_ws + 256);

    var_kernel<<<NB, 256, 0, stream>>>(pc, vars);

    size_t avail = ws_size > 256 ? ws_size - 256 : 0;
    if (avail >= (size_t)8 * BN * sizeof(float)) {
        nn_kernel<8><<<64 * 8, 256, 0, stream>>>(pc, pmin);
        final_kernel<8><<<1, 1024, 0, stream>>>(pmin, vars, out);
    } else if (avail >= (size_t)4 * BN * sizeof(float)) {
        nn_kernel<4><<<64 * 4, 256, 0, stream>>>(pc, pmin);
        final_kernel<4><<<1, 1024, 0, stream>>>(pmin, vars, out);
    } else if (avail >= (size_t)2 * BN * sizeof(float)) {
        nn_kernel<2><<<64 * 2, 256, 0, stream>>>(pc, pmin);
        final_kernel<2><<<1, 1024, 0, stream>>>(pmin, vars, out);
    } else {
        nn_kernel<1><<<64, 256, 0, stream>>>(pc, pmin);
        final_kernel<1><<<1, 1024, 0, stream>>>(pmin, vars, out);
    }
}

// Round 2
// 28.826 us; speedup vs baseline: 2.3333x; 2.3333x over previous
//
#include <hip/hip_runtime.h>
#include <math.h>

#define NB    4
#define NPTS  4096
#define BN    (NB * NPTS)
#define BLOCK 256
#define IT    4                    // queries per thread
#define QPB   (BLOCK * IT)         // 1024 queries per block
#define NQB   (NPTS / QPB)         // 4 query-blocks per batch
#define NJ    32                   // j-chunks
#define JC    (NPTS / NJ)          // 128 points per chunk

__device__ inline float wave_sum(float v) {
#pragma unroll
    for (int o = 32; o > 0; o >>= 1) v += __shfl_xor(v, o);
    return v;
}

// --- Kernel 1: nearest-neighbor partial min (gram form) + centroid partials ---
// grid = 16 qblocks * NJ chunks = 512 blocks of 256 threads.
__global__ __launch_bounds__(256) void nn_kernel(const float* __restrict__ pc,
                                                 unsigned int* __restrict__ pmin,
                                                 float* __restrict__ cpart) {
    __shared__ float4 lpt[JC];
    __shared__ float sbuf[4];

    int blk = blockIdx.x;
    int jc  = blk % NJ;
    int qb  = blk / NJ;            // 0..15 global query block
    int b   = qb >> 2;             // batch (NQB=4 qblocks per batch)
    int iq0 = (qb & 3) * QPB;
    int jbase = jc * JC;
    const float* p = pc + (size_t)b * NPTS * 3;
    int t = threadIdx.x;

    // stage chunk: (x, y, z, |x|^2)
    if (t < JC) {
        int jg = jbase + t;
        float x = p[3*jg+0], y = p[3*jg+1], z = p[3*jg+2];
        lpt[t] = make_float4(x, y, z, fmaf(x, x, fmaf(y, y, z * z)));
    }

    // load 4 query points into registers
    float qx[IT], qy[IT], qz[IT], ri[IT], ax[IT], ay[IT], az[IT], m[IT];
#pragma unroll
    for (int k = 0; k < IT; ++k) {
        int i = iq0 + t + k * BLOCK;
        float x = p[3*i+0], y = p[3*i+1], z = p[3*i+2];
        qx[k] = x; qy[k] = y; qz[k] = z;
        ri[k] = fmaf(x, x, fmaf(y, y, z * z));
        ax[k] = -2.f * x; ay[k] = -2.f * y; az[k] = -2.f * z;
        m[k] = 1e30f;
    }
    __syncthreads();

    bool diag = ((jbase >> 10) == (qb & 3));   // chunk lies inside this block's query range
    if (diag) {
        int idl[IT];
#pragma unroll
        for (int k = 0; k < IT; ++k) idl[k] = iq0 + t + k * BLOCK - jbase;
#pragma unroll 4
        for (int j = 0; j < JC; ++j) {
            float4 q = lpt[j];
#pragma unroll
            for (int k = 0; k < IT; ++k) {
                float e = fmaf(ax[k], q.x, fmaf(ay[k], q.y, fmaf(az[k], q.z, q.w)));
                m[k] = fminf(m[k], (j == idl[k]) ? 1e30f : e);
            }
        }
    } else {
#pragma unroll 4
        for (int j = 0; j < JC; ++j) {
            float4 q = lpt[j];
#pragma unroll
            for (int k = 0; k < IT; ++k) {
                float e = fmaf(ax[k], q.x, fmaf(ay[k], q.y, fmaf(az[k], q.z, q.w)));
                m[k] = fminf(m[k], e);
            }
        }
    }

#pragma unroll
    for (int k = 0; k < IT; ++k) {
        float mm = fmaxf(ri[k] + m[k], 0.f);   // clamp like jnp.maximum(.,0)
        atomicMin(&pmin[b * NPTS + iq0 + t + k * BLOCK], __float_as_uint(mm));
    }

    // centroid partial sums: only the jc==0 block for each qblock (queries already in regs)
    if (jc == 0) {
        float sx = 0.f, sy = 0.f, sz = 0.f;
#pragma unroll
        for (int k = 0; k < IT; ++k) { sx += qx[k]; sy += qy[k]; sz += qz[k]; }
        int lane = t & 63, w = t >> 6;
        sx = wave_sum(sx); sy = wave_sum(sy); sz = wave_sum(sz);
        if (lane == 0) sbuf[w] = sx;
        __syncthreads();
        float tx = sbuf[0] + sbuf[1] + sbuf[2] + sbuf[3];
        __syncthreads();
        if (lane == 0) sbuf[w] = sy;
        __syncthreads();
        float ty = sbuf[0] + sbuf[1] + sbuf[2] + sbuf[3];
        __syncthreads();
        if (lane == 0) sbuf[w] = sz;
        __syncthreads();
        float tz = sbuf[0] + sbuf[1] + sbuf[2] + sbuf[3];
        if (t == 0) {
            cpart[qb * 3 + 0] = tx;
            cpart[qb * 3 + 1] = ty;
            cpart[qb * 3 + 2] = tz;
        }
    }
}

// --- Kernel 2: centroid finish, variance, exp penalty, final scalar ---
__global__ __launch_bounds__(1024) void final_kernel(const float* __restrict__ pc,
                                                     const unsigned int* __restrict__ pmin,
                                                     const float* __restrict__ cpart,
                                                     float* __restrict__ out) {
    __shared__ float cen[NB][4];   // cx, cy, cz (centroid)
    __shared__ float sbuf[16];
    int t = threadIdx.x;

    if (t < NB) {
        float cx = 0.f, cy = 0.f, cz = 0.f;
#pragma unroll
        for (int q = 0; q < NQB; ++q) {
            cx += cpart[(t * NQB + q) * 3 + 0];
            cy += cpart[(t * NQB + q) * 3 + 1];
            cz += cpart[(t * NQB + q) * 3 + 2];
        }
        cen[t][0] = cx * (1.f / NPTS);
        cen[t][1] = cy * (1.f / NPTS);
        cen[t][2] = cz * (1.f / NPTS);
    }
    __syncthreads();

    float s1[NB], s2[NB], es = 0.f;
#pragma unroll
    for (int b = 0; b < NB; ++b) { s1[b] = 0.f; s2[b] = 0.f; }

#pragma unroll
    for (int k = 0; k < 16; ++k) {           // 16384 points / 1024 threads
        int g = t + k * 1024;
        int b = k >> 2;                      // 4096 pts per batch, compile-time
        float x = pc[3*g+0], y = pc[3*g+1], z = pc[3*g+2];
        float dx = x - cen[b][0], dy = y - cen[b][1], dz = z - cen[b][2];
        float d2 = fmaf(dx, dx, fmaf(dy, dy, dz * dz));
        s1[b] += sqrtf(d2);
        s2[b] += d2;
        es += __expf(-5.f * __uint_as_float(pmin[g]));
    }

    int lane = t & 63, w = t >> 6;
    float tot[9];
    float vals[9] = { s1[0], s2[0], s1[1], s2[1], s1[2], s2[2], s1[3], s2[3], es };
#pragma unroll
    for (int r = 0; r < 9; ++r) {
        float v = wave_sum(vals[r]);
        __syncthreads();
        if (lane == 0) sbuf[w] = v;
        __syncthreads();
        float s = 0.f;
#pragma unroll
        for (int q = 0; q < 16; ++q) s += sbuf[q];
        tot[r] = s;
    }

    if (t == 0) {
        float vsum = 0.f;
#pragma unroll
        for (int b = 0; b < NB; ++b) {
            float S1 = tot[2*b], S2 = tot[2*b+1];
            vsum += (S2 - S1 * S1 * (1.f / NPTS)) * (1.f / (NPTS - 1));
        }
        out[0] = vsum * (1.f / NB) + tot[8] * (1.f / BN);
    }
}

extern "C" void kernel_launch(void* const* d_in, const int* in_sizes, int n_in,
                              void* d_out, int out_size, void* d_ws, size_t ws_size,
                              hipStream_t stream) {
    const float* pc = (const float*)d_in[0];
    float* out = (float*)d_out;
    float* cpart = (float*)d_ws;                               // 48 floats
    unsigned int* pmin = (unsigned int*)((char*)d_ws + 256);   // BN uints

    // init pmin to a huge positive float (0x7f7f7f7f ~ 3.39e38)
    hipMemsetAsync(pmin, 0x7f, (size_t)BN * sizeof(unsigned int), stream);

    nn_kernel<<<16 * NJ, BLOCK, 0, stream>>>(pc, pmin, cpart);
    final_kernel<<<1, 1024, 0, stream>>>(pc, pmin, cpart, out);
}

// Round 3
// 21.033 us; speedup vs baseline: 3.1979x; 1.3705x over previous
//
#include <hip/hip_runtime.h>
#include <math.h>

#define NB    4
#define NPTS  4096
#define BN    (NB * NPTS)
#define BLOCK 256
#define IT    4                    // queries per thread
#define QPB   (BLOCK * IT)         // 1024 queries per block
#define NQB   (NPTS / QPB)         // 4 query-blocks per batch

__device__ inline float wave_sum(float v) {
#pragma unroll
    for (int o = 32; o > 0; o >>= 1) v += __shfl_xor(v, o);
    return v;
}

// --- Kernel 1: per-chunk NN partial min (gram form, no ri) + centroid partials ---
// grid = 16 qblocks * NJ chunks. Plain stores -> no memset, no atomics.
template <int NJ>
__global__ __launch_bounds__(256) void nn_kernel(const float* __restrict__ pc,
                                                 float* __restrict__ pmin,
                                                 float* __restrict__ cpart) {
    constexpr int JC = NPTS / NJ;
    __shared__ float4 lpt[JC];
    __shared__ float sbuf[4];

    int blk = blockIdx.x;
    int jc  = blk % NJ;
    int qb  = blk / NJ;            // 0..15 global query block
    int b   = qb >> 2;             // batch (NQB=4 qblocks per batch)
    int iq0 = (qb & 3) * QPB;
    int jbase = jc * JC;
    const float* p = pc + (size_t)b * NPTS * 3;
    int t = threadIdx.x;

    // stage chunk: (x, y, z, |x|^2)
    for (int j = t; j < JC; j += BLOCK) {
        int jg = jbase + j;
        float x = p[3*jg+0], y = p[3*jg+1], z = p[3*jg+2];
        lpt[j] = make_float4(x, y, z, fmaf(x, x, fmaf(y, y, z * z)));
    }

    // 4 query points, prefolded as (-2x, -2y, -2z)
    float ax[IT], ay[IT], az[IT], m[IT];
#pragma unroll
    for (int k = 0; k < IT; ++k) {
        int i = iq0 + t + k * BLOCK;
        ax[k] = -2.f * p[3*i+0];
        ay[k] = -2.f * p[3*i+1];
        az[k] = -2.f * p[3*i+2];
        m[k] = 1e30f;
    }
    __syncthreads();

    if ((jbase >> 10) == (qb & 3)) {            // chunk overlaps this block's queries
        int idl[IT];
#pragma unroll
        for (int k = 0; k < IT; ++k) idl[k] = iq0 + t + k * BLOCK - jbase;
#pragma unroll 4
        for (int j = 0; j < JC; ++j) {
            float4 q = lpt[j];
#pragma unroll
            for (int k = 0; k < IT; ++k) {
                float e = fmaf(ax[k], q.x, fmaf(ay[k], q.y, fmaf(az[k], q.z, q.w)));
                m[k] = fminf(m[k], (j == idl[k]) ? 1e30f : e);
            }
        }
    } else {
#pragma unroll 8
        for (int j = 0; j < JC; ++j) {
            float4 q = lpt[j];
#pragma unroll
            for (int k = 0; k < IT; ++k) {
                float e = fmaf(ax[k], q.x, fmaf(ay[k], q.y, fmaf(az[k], q.z, q.w)));
                m[k] = fminf(m[k], e);
            }
        }
    }

#pragma unroll
    for (int k = 0; k < IT; ++k)
        pmin[(size_t)jc * BN + b * NPTS + iq0 + t + k * BLOCK] = m[k];

    // centroid partials: one chunk per qblock does it (queries already in regs, as -2x)
    if (jc == 0) {
        float sx = 0.f, sy = 0.f, sz = 0.f;
#pragma unroll
        for (int k = 0; k < IT; ++k) { sx += ax[k]; sy += ay[k]; sz += az[k]; }
        int lane = t & 63, w = t >> 6;
        sx = wave_sum(sx); sy = wave_sum(sy); sz = wave_sum(sz);
        __syncthreads();
        if (lane == 0) sbuf[w] = sx;
        __syncthreads();
        float tx = sbuf[0] + sbuf[1] + sbuf[2] + sbuf[3];
        __syncthreads();
        if (lane == 0) sbuf[w] = sy;
        __syncthreads();
        float ty = sbuf[0] + sbuf[1] + sbuf[2] + sbuf[3];
        __syncthreads();
        if (lane == 0) sbuf[w] = sz;
        __syncthreads();
        float tz = sbuf[0] + sbuf[1] + sbuf[2] + sbuf[3];
        if (t == 0) {
            cpart[qb * 3 + 0] = -0.5f * tx;    // undo the -2 prefold
            cpart[qb * 3 + 1] = -0.5f * ty;
            cpart[qb * 3 + 2] = -0.5f * tz;
        }
    }
}

// --- Kernel 2: parallel combine: min over chunks, exp penalty, variance parts ---
// grid = 64 blocks * 256 threads = one thread per query.
template <int NJ>
__global__ __launch_bounds__(256) void combine_kernel(const float* __restrict__ pc,
                                                      const float* __restrict__ pmin,
                                                      const float* __restrict__ cpart,
                                                      float* __restrict__ bpart) {
    __shared__ float sbuf[4];
    int blk = blockIdx.x;          // 0..63 (16 per batch)
    int b   = blk >> 4;
    int t   = threadIdx.x;
    int g   = blk * BLOCK + t;     // global query index

    float cx = 0.f, cy = 0.f, cz = 0.f;
#pragma unroll
    for (int q = 0; q < NQB; ++q) {
        cx += cpart[(b * NQB + q) * 3 + 0];
        cy += cpart[(b * NQB + q) * 3 + 1];
        cz += cpart[(b * NQB + q) * 3 + 2];
    }
    cx *= (1.f / NPTS); cy *= (1.f / NPTS); cz *= (1.f / NPTS);

    float m = pmin[g];
#pragma unroll
    for (int jc = 1; jc < NJ; ++jc)
        m = fminf(m, pmin[(size_t)jc * BN + g]);

    float x = pc[3*g+0], y = pc[3*g+1], z = pc[3*g+2];
    float ri = fmaf(x, x, fmaf(y, y, z * z));
    float mm = fmaxf(ri + m, 0.f);             // = max(||xi||^2 + min_j(rj - 2xi.xj), 0)
    float es = __expf(-5.f * mm);

    float dx = x - cx, dy = y - cy, dz = z - cz;
    float d2 = fmaf(dx, dx, fmaf(dy, dy, dz * dz));
    float vals[3] = { sqrtf(d2), d2, es };

    int lane = t & 63, w = t >> 6;
    float tot[3];
#pragma unroll
    for (int r = 0; r < 3; ++r) {
        float v = wave_sum(vals[r]);
        __syncthreads();
        if (lane == 0) sbuf[w] = v;
        __syncthreads();
        tot[r] = sbuf[0] + sbuf[1] + sbuf[2] + sbuf[3];
    }
    if (t == 0) {
        bpart[blk * 3 + 0] = tot[0];           // sum |x - c|   (per batch: block in one batch)
        bpart[blk * 3 + 1] = tot[1];           // sum |x - c|^2
        bpart[blk * 3 + 2] = tot[2];           // sum exp(-5 m)
    }
}

// --- Kernel 3: one wave: variance per batch, final scalar ---
__global__ __launch_bounds__(64) void finish_kernel(const float* __restrict__ bpart,
                                                    float* __restrict__ out) {
    int t = threadIdx.x;           // 64 block-partials, 16 per batch
    float s1 = bpart[t*3+0], s2 = bpart[t*3+1], es = bpart[t*3+2];
    float g1 = s1, g2 = s2;
#pragma unroll
    for (int o = 1; o < 16; o <<= 1) {
        g1 += __shfl_xor(g1, o);
        g2 += __shfl_xor(g2, o);
    }
    float et = es;
#pragma unroll
    for (int o = 1; o < 64; o <<= 1) et += __shfl_xor(et, o);

    float vs = 0.f;
#pragma unroll
    for (int b = 0; b < NB; ++b) {
        float S1 = __shfl(g1, b * 16);
        float S2 = __shfl(g2, b * 16);
        vs += (S2 - S1 * S1 * (1.f / NPTS)) * (1.f / (NPTS - 1));
    }
    if (t == 0) out[0] = vs * (1.f / NB) + et * (1.f / BN);
}

template <int NJ>
static void run(const float* pc, float* out, void* d_ws, hipStream_t stream) {
    float* pmin  = (float*)d_ws;
    float* cpart = (float*)((char*)d_ws + (size_t)NJ * BN * sizeof(float));
    float* bpart = cpart + 48;
    nn_kernel<NJ><<<16 * NJ, BLOCK, 0, stream>>>(pc, pmin, cpart);
    combine_kernel<NJ><<<64, BLOCK, 0, stream>>>(pc, pmin, cpart, bpart);
    finish_kernel<<<1, 64, 0, stream>>>(bpart, out);
}

extern "C" void kernel_launch(void* const* d_in, const int* in_sizes, int n_in,
                              void* d_out, int out_size, void* d_ws, size_t ws_size,
                              hipStream_t stream) {
    const float* pc = (const float*)d_in[0];
    float* out = (float*)d_out;
    auto need = [](int nj) { return (size_t)nj * BN * sizeof(float) + 1024; };

    if      (ws_size >= need(64)) run<64>(pc, out, d_ws, stream);
    else if (ws_size >= need(32)) run<32>(pc, out, d_ws, stream);
    else if (ws_size >= need(16)) run<16>(pc, out, d_ws, stream);
    else if (ws_size >= need(8))  run<8> (pc, out, d_ws, stream);
    else                          run<4> (pc, out, d_ws, stream);
}